// Round 15
// baseline (129.400 us; speedup 1.0000x reference)
//
#include <hip/hip_runtime.h>
#include <hip/hip_bf16.h>
#include <stdint.h>

#define BB 16
#define NN 4096
#define MM 1024
#define C1 128
#define C2 256
#define CIN 384
#define CO 256
#define ROWS (BB * NN)

typedef __attribute__((ext_vector_type(8))) short bf16x8;
typedef __attribute__((ext_vector_type(4))) float f32x4;

__device__ inline float u2f(uint32_t u) { union { uint32_t u; float f; } v; v.u = u; return v.f; }
__device__ inline uint32_t f2u(float f) { union { float f; uint32_t u; } v; v.f = f; return v.u; }
// round-to-nearest-even f32 -> bf16 (scalar; use pk2bf for pairs)
__device__ inline unsigned short f2bf(float f) {
  uint32_t u = f2u(f);
  uint32_t r = u + 0x7fffu + ((u >> 16) & 1u);
  return (unsigned short)(r >> 16);
}
__device__ inline float bflo(uint32_t w) { return u2f(w << 16); }
__device__ inline float bfhi(uint32_t w) { return u2f(w & 0xffff0000u); }
// packed RNE f32x2 -> bf16x2 (v_cvt_pk_bf16_f32; bit-identical to f2bf pair)
__device__ inline uint32_t pk2bf(float lo, float hi) {
  union { __hip_bfloat162 h; uint32_t u; } c;
  c.h = __float22bfloat162_rn(make_float2(lo, hi));
  return c.u;
}

// ------------------- three_nn + interp + concat + weight prep (one launch)
// NN blocks are bids 0..2047; weight-prep strips are bids 2048..2687 (tail).
// Sorted top-3 insert via v_med3_f32 (bit-exact selection, no rounding).
// SoA-4x candidate loop: qx/qy/qz arrays, each lane handles 4 consecutive
// candidates per step via 3 ds_read_b128 -> LDS instrs 1.0 -> 0.75/candidate
// (the LDS unit is co-dominant with VALU issue in this loop), addressing
// amortized 4x. Distance formula & insert order per lane unchanged
// (ascending j, strict <) -> selection identical to the reference.
#define NN_INS(dd, jj_)                                            \
  {                                                                \
    bool c0 = (dd) < e0, c1 = (dd) < e1, c2 = (dd) < e2;           \
    e2 = __builtin_amdgcn_fmed3f(e1, e2, (dd));                    \
    e1 = __builtin_amdgcn_fmed3f(e0, e1, (dd));                    \
    e0 = fminf(e0, (dd));                                          \
    i2 = c2 ? (c1 ? i1 : (jj_)) : i2;                              \
    i1 = c1 ? (c0 ? i0 : (jj_)) : i1;                              \
    i0 = c0 ? (jj_) : i0;                                          \
  }

__global__ __launch_bounds__(256) void nn_interp(const float* __restrict__ xyz1,
                                                 const float* __restrict__ xyz2,
                                                 const float* __restrict__ points2,
                                                 const float* __restrict__ points1,
                                                 const float* __restrict__ W0,
                                                 const float* __restrict__ W1,
                                                 unsigned short* __restrict__ W0t,
                                                 unsigned short* __restrict__ W1t,
                                                 float* __restrict__ stats,
                                                 unsigned short* __restrict__ X) {
  int t = threadIdx.x, bid = blockIdx.x;
  if (bid >= 2048) {  // ---- weight prep strips (tail) ----
    int wb = bid - 2048;
    if (wb == 0) { stats[t] = 0.f; stats[256 + t] = 0.f; }
    if (wb == 1) { stats[512 + t] = 0.f; stats[768 + t] = 0.f; }
    if (wb < 384) {
      int i = wb * 256 + t;           // W0t[n][k], k over 384
      int n = i / CIN, k = i - n * CIN;
      W0t[i] = f2bf(W0[(size_t)k * CO + n]);
    } else {
      int n = wb - 384;               // W1t[n][k], k = t
      W1t[n * CO + t] = f2bf(W1[(size_t)t * CO + n]);
    }
    return;
  }
  __shared__ __align__(16) float qx[MM];  // SoA candidate coords, 12 KB
  __shared__ __align__(16) float qy[MM];
  __shared__ __align__(16) float qz[MM];
  __shared__ int sid[96];
  __shared__ float swt[96];
  int b = bid >> 7;                 // 128 blocks per batch
  int qbase = (bid & 127) << 5;     // 32 queries per block
  const float* x2 = xyz2 + (size_t)b * MM * 3;
  for (int j = t; j < MM; j += 256) {
    const float* s = x2 + j * 3;
    qx[j] = s[0]; qy[j] = s[1]; qz[j] = s[2];
  }
  __syncthreads();
  int n = qbase + (t >> 3);
  int tq = t & 7;
  const float* p = xyz1 + ((size_t)b * NN + n) * 3;
  float px = p[0], py = p[1], pz = p[2];
  float e0 = 1e30f, e1 = 1e30f, e2 = 1e30f;
  int i0 = 0, i1 = 0, i2 = 0;
  // lane tq handles candidates j = jj*32 + tq*4 .. +3 (ascending within lane)
#pragma unroll 4
  for (int jj = 0; jj < MM / 32; ++jj) {
    int j = jj * 32 + tq * 4;
    float4 x4 = *(const float4*)&qx[j];
    float4 y4 = *(const float4*)&qy[j];
    float4 z4 = *(const float4*)&qz[j];
    float dx0 = px - x4.x, dy0 = py - y4.x, dz0 = pz - z4.x;
    float d0 = dx0 * dx0 + dy0 * dy0 + dz0 * dz0;
    float dx1 = px - x4.y, dy1 = py - y4.y, dz1 = pz - z4.y;
    float d1 = dx1 * dx1 + dy1 * dy1 + dz1 * dz1;
    float dx2 = px - x4.z, dy2 = py - y4.z, dz2 = pz - z4.z;
    float d2 = dx2 * dx2 + dy2 * dy2 + dz2 * dz2;
    float dx3 = px - x4.w, dy3 = py - y4.w, dz3 = pz - z4.w;
    float d3 = dx3 * dx3 + dy3 * dy3 + dz3 * dz3;
    NN_INS(d0, j);
    NN_INS(d1, j + 1);
    NN_INS(d2, j + 2);
    NN_INS(d3, j + 3);
  }
#pragma unroll
  for (int mk = 1; mk <= 4; mk <<= 1) {
    float f0 = __shfl_xor(e0, mk), f1 = __shfl_xor(e1, mk), f2 = __shfl_xor(e2, mk);
    int j0 = __shfl_xor(i0, mk), j1 = __shfl_xor(i1, mk), j2 = __shfl_xor(i2, mk);
    NN_INS(f0, j0);
    NN_INS(f1, j1);
    NN_INS(f2, j2);
  }
  if (tq == 0) {
    float a0 = fmaxf(e0, 1e-10f), a1 = fmaxf(e1, 1e-10f), a2 = fmaxf(e2, 1e-10f);
    float v0 = 1.f / a0, v1 = 1.f / a1, v2 = 1.f / a2;
    float inv = 1.f / (v0 + v1 + v2);
    int qi = t >> 3;
    sid[qi * 3 + 0] = i0; sid[qi * 3 + 1] = i1; sid[qi * 3 + 2] = i2;
    swt[qi * 3 + 0] = v0 * inv; swt[qi * 3 + 1] = v1 * inv; swt[qi * 3 + 2] = v2 * inv;
  }
  __syncthreads();
  // ---- interp + concat: thread t owns row r = t>>3, chunk lane s = t&7.
  // Chunks s+8i: i=0..3 -> points2 (interp), i=4,5 -> points1 (copy).
  {
    int r = t >> 3, s = t & 7;
    size_t grow = (size_t)b * NN + qbase + r;
    unsigned short* xr = X + grow * CIN;
    const float* p2 = points2 + (size_t)b * MM * C2;
    float w0 = swt[r * 3], w1 = swt[r * 3 + 1], w2 = swt[r * 3 + 2];
    const float* a0 = p2 + (size_t)sid[r * 3 + 0] * C2;
    const float* a1 = p2 + (size_t)sid[r * 3 + 1] * C2;
    const float* a2 = p2 + (size_t)sid[r * 3 + 2] * C2;
#pragma unroll
    for (int i = 0; i < 4; ++i) {
      int c0 = (s + 8 * i) * 8;
      float4 x0 = *(const float4*)(a0 + c0), x1 = *(const float4*)(a0 + c0 + 4);
      float4 y0 = *(const float4*)(a1 + c0), y1 = *(const float4*)(a1 + c0 + 4);
      float4 z0 = *(const float4*)(a2 + c0), z1 = *(const float4*)(a2 + c0 + 4);
      uint4 o4;
      o4.x = pk2bf(w0 * x0.x + w1 * y0.x + w2 * z0.x, w0 * x0.y + w1 * y0.y + w2 * z0.y);
      o4.y = pk2bf(w0 * x0.z + w1 * y0.z + w2 * z0.z, w0 * x0.w + w1 * y0.w + w2 * z0.w);
      o4.z = pk2bf(w0 * x1.x + w1 * y1.x + w2 * z1.x, w0 * x1.y + w1 * y1.y + w2 * z1.y);
      o4.w = pk2bf(w0 * x1.z + w1 * y1.z + w2 * z1.z, w0 * x1.w + w1 * y1.w + w2 * z1.w);
      *(uint4*)(xr + c0) = o4;
    }
    const float* ap = points1 + grow * C1;
#pragma unroll
    for (int i = 0; i < 2; ++i) {
      int c0 = (s + 8 * i) * 8;
      float4 x0 = *(const float4*)(ap + c0), x1 = *(const float4*)(ap + c0 + 4);
      uint4 o4;
      o4.x = pk2bf(x0.x, x0.y); o4.y = pk2bf(x0.z, x0.w);
      o4.z = pk2bf(x1.x, x1.y); o4.w = pk2bf(x1.z, x1.w);
      *(uint4*)(xr + C2 + c0) = o4;
    }
  }
}

// ---------------------------------------------------------------- bf16 GEMM
// C[m][n] = sum_k A'[m][k] * Bt[n][k];  A' = FUSE ? relu(A*sc+sh) : A.
// (round-11 proven form) Ping-pong A regs + counted vmcnt before raw
// s_barrier: vmcnt(4) waits only the 4 older B gload_lds; A-register loads
// stay in flight across the barrier. Prefetch slots contain RAW loads only.
__device__ inline void gload_lds16(const void* g, void* l) {
  __builtin_amdgcn_global_load_lds(
      (const __attribute__((address_space(1))) void*)g,
      (__attribute__((address_space(3))) void*)l, 16, 0, 0);
}

template <int K, bool FUSE>
__global__ __launch_bounds__(256, 3) void gemm_nt(const unsigned short* __restrict__ A,
                                                  const unsigned short* __restrict__ Bt,
                                                  unsigned short* __restrict__ C,
                                                  float* __restrict__ stats,
                                                  const float* __restrict__ statsPrev,
                                                  const float* __restrict__ g,
                                                  const float* __restrict__ be) {
  constexpr int NT = K / 64;
  __shared__ unsigned short lB[2][128 * 64];  // [buf][n][k] swizzled chunks
  __shared__ float sdat[256];
  __shared__ float lscsh[FUSE ? 512 : 4];
  int t = threadIdx.x;
  int lane = t & 63, w = t >> 6;
  // pair-XCD swizzle: the two 128-col panels of one row-tile get bids 8 apart
  int gb = blockIdx.x >> 4, rb = blockIdx.x & 15;
  int pq = rb >> 3, ti = (gb << 3) + (rb & 7);
  int m0 = ti * 128, n0 = pq * 128;
  int lrow = lane >> 3;                       // 0..7
  int lcol = (((lane & 7) ^ lrow) << 3);      // T2 source-side swizzled chunk

#define STAGE_B(buf, tt_)                                                      \
  {                                                                            \
    _Pragma("unroll") for (int i = 0; i < 4; ++i) {                            \
      int row = i * 32 + w * 8 + lrow;                                         \
      gload_lds16(Bt + (size_t)(n0 + row) * K + (tt_) * 64 + lcol,             \
                  &lB[buf][i * 2048 + w * 512]);                               \
    }                                                                          \
    asm volatile("" ::: "memory");  /* pin issue order: gloads before A */     \
  }

  const unsigned short* Ab = A + (size_t)(m0 + w * 32 + (lane & 15)) * K + (lane >> 4) * 8;
#define LOAD_A(dst, tt_)                                                       \
  {                                                                            \
    dst[0] = *(const uint4*)(Ab + (tt_) * 64);                                 \
    dst[1] = *(const uint4*)(Ab + (size_t)16 * K + (tt_) * 64);                \
    dst[2] = *(const uint4*)(Ab + (tt_) * 64 + 32);                            \
    dst[3] = *(const uint4*)(Ab + (size_t)16 * K + (tt_) * 64 + 32);           \
  }

  uint4 afA[4], afB[4];
  STAGE_B(0, 0);
  LOAD_A(afA, 0);
  sdat[t] = 0.f;
  if (FUSE) {
    float mean = statsPrev[t] * (1.f / ROWS);
    float var = statsPrev[256 + t] * (1.f / ROWS) - mean * mean;
    float sc = g[t] * rsqrtf(var + 1e-3f);
    lscsh[t] = sc;
    lscsh[256 + t] = be[t] - mean * sc;
  }
  __syncthreads();  // prologue: full drain, B(0) visible

  f32x4 acc[2][8] = {};

#define COMPUTE(buf, tt_, AF)                                                  \
  {                                                                            \
    _Pragma("unroll") for (int kk = 0; kk < 2; ++kk) {                         \
      int ko = kk * 32 + (lane >> 4) * 8;                                      \
      bf16x8 bfr[8];                                                           \
      _Pragma("unroll") for (int n2 = 0; n2 < 8; ++n2) {                       \
        int row = n2 * 16 + (lane & 15);                                       \
        bfr[n2] = *(const bf16x8*)&lB[buf][row * 64 + (ko ^ ((row & 7) << 3))];\
      }                                                                        \
      bf16x8 af[2];                                                            \
      _Pragma("unroll") for (int m = 0; m < 2; ++m) {                          \
        union { uint4 u; bf16x8 h; uint32_t wv[4]; } cv;                       \
        cv.u = AF[kk * 2 + m];                                                 \
        if (FUSE) {                                                            \
          int cb = (tt_) * 64 + ko;                                            \
          float4 sa = *(const float4*)&lscsh[cb];                              \
          float4 sb = *(const float4*)&lscsh[cb + 4];                          \
          float4 ha = *(const float4*)&lscsh[256 + cb];                        \
          float4 hb = *(const float4*)&lscsh[256 + cb + 4];                    \
          float scf[8] = {sa.x, sa.y, sa.z, sa.w, sb.x, sb.y, sb.z, sb.w};     \
          float shf[8] = {ha.x, ha.y, ha.z, ha.w, hb.x, hb.y, hb.z, hb.w};     \
          _Pragma("unroll") for (int q_ = 0; q_ < 4; ++q_) {                   \
            float lo = fmaxf(bflo(cv.wv[q_]) * scf[2 * q_] + shf[2 * q_], 0.f);\
            float hi = fmaxf(bfhi(cv.wv[q_]) * scf[2 * q_ + 1] + shf[2 * q_ + 1], 0.f); \
            cv.wv[q_] = pk2bf(lo, hi);                                         \
          }                                                                    \
        }                                                                      \
        af[m] = cv.h;                                                          \
      }                                                                        \
      _Pragma("unroll") for (int m = 0; m < 2; ++m)                            \
        _Pragma("unroll") for (int n2 = 0; n2 < 8; ++n2)                       \
          acc[m][n2] = __builtin_amdgcn_mfma_f32_16x16x32_bf16(af[m], bfr[n2], acc[m][n2], 0, 0, 0); \
    }                                                                          \
  }

#define CBAR()                                                                 \
  {                                                                            \
    asm volatile("s_waitcnt vmcnt(4)" ::: "memory");                           \
    __builtin_amdgcn_s_barrier();                                              \
  }

#pragma unroll
  for (int tt = 0; tt < NT; tt += 2) {
    STAGE_B(1, tt + 1);
    LOAD_A(afB, tt + 1);
    COMPUTE(0, tt, afA);
    CBAR();
    if (tt + 2 < NT) {
      STAGE_B(0, tt + 2);
      LOAD_A(afA, tt + 2);
    }
    COMPUTE(1, tt + 1, afB);
    if (tt + 2 < NT) CBAR();
  }
#undef STAGE_B
#undef LOAD_A
#undef COMPUTE
#undef CBAR

  // ---- C write (bf16, raw pre-BN values) ----
  int crow0 = m0 + w * 32 + (lane >> 4) * 4;
  int ccol0 = n0 + (lane & 15);
#pragma unroll
  for (int m = 0; m < 2; ++m)
#pragma unroll
    for (int n2 = 0; n2 < 8; ++n2) {
      size_t rb2 = (size_t)(crow0 + m * 16);
      int cc = ccol0 + n2 * 16;
#pragma unroll
      for (int j = 0; j < 4; ++j)
        C[(rb2 + j) * CO + cc] = f2bf(acc[m][n2][j]);
    }
  // ---- fused BN stats ----
#pragma unroll
  for (int n2 = 0; n2 < 8; ++n2) {
    float s = 0.f, qq = 0.f;
#pragma unroll
    for (int m = 0; m < 2; ++m)
#pragma unroll
      for (int j = 0; j < 4; ++j) { float v = acc[m][n2][j]; s += v; qq += v * v; }
    s += __shfl_xor(s, 16); qq += __shfl_xor(qq, 16);
    s += __shfl_xor(s, 32); qq += __shfl_xor(qq, 32);
    if (lane < 16) {
      int cl = n2 * 16 + lane;
      atomicAdd(&sdat[cl], s);
      atomicAdd(&sdat[128 + cl], qq);
    }
  }
  __syncthreads();
  if (t < 128) {
    atomicAdd(&stats[n0 + t], sdat[t]);
    atomicAdd(&stats[256 + n0 + t], sdat[128 + t]);
  }
}

// ------------------- BN+ReLU apply, fp32 out (finalize folded into prologue)
__global__ __launch_bounds__(256) void apply_f32(const unsigned short* __restrict__ Y,
                                                 const float* __restrict__ stats2,
                                                 const float* __restrict__ g,
                                                 const float* __restrict__ be,
                                                 float* __restrict__ out) {
  __shared__ float sc[256], sh[256];
  int t = threadIdx.x;
  {
    float mean = stats2[t] * (1.f / ROWS);
    float var = stats2[256 + t] * (1.f / ROWS) - mean * mean;
    float s = g[t] * rsqrtf(var + 1e-3f);
    sc[t] = s;
    sh[t] = be[t] - mean * s;
  }
  __syncthreads();
  size_t base = ((size_t)blockIdx.x * 256 + t) * 8;
  int c0 = (int)(base & 255);
  uint4 v = *(const uint4*)(Y + base);
  uint32_t wv[4] = {v.x, v.y, v.z, v.w};
  float o[8];
#pragma unroll
  for (int q = 0; q < 4; ++q) {
    o[2 * q]     = fmaxf(bflo(wv[q]) * sc[c0 + 2 * q] + sh[c0 + 2 * q], 0.f);
    o[2 * q + 1] = fmaxf(bfhi(wv[q]) * sc[c0 + 2 * q + 1] + sh[c0 + 2 * q + 1], 0.f);
  }
  *(float4*)(out + base) = make_float4(o[0], o[1], o[2], o[3]);
  *(float4*)(out + base + 4) = make_float4(o[4], o[5], o[6], o[7]);
}

extern "C" void kernel_launch(void* const* d_in, const int* in_sizes, int n_in,
                              void* d_out, int out_size, void* d_ws, size_t ws_size,
                              hipStream_t stream) {
  const float* xyz1    = (const float*)d_in[0];
  const float* xyz2    = (const float*)d_in[1];
  const float* points1 = (const float*)d_in[2];
  const float* points2 = (const float*)d_in[3];
  const float* W0      = (const float*)d_in[4];
  const float* g0      = (const float*)d_in[6];
  const float* be0     = (const float*)d_in[7];
  const float* W1      = (const float*)d_in[8];
  const float* g1      = (const float*)d_in[10];
  const float* be1     = (const float*)d_in[11];
  float* out = (float*)d_out;

  // workspace layout (bytes)
  char* ws = (char*)d_ws;
  unsigned short* X   = (unsigned short*)(ws);                       // ROWS*384 bf16 (reused for Y2)
  unsigned short* Y1  = (unsigned short*)(ws + 50331648);            // ROWS*256 bf16
  unsigned short* W0t = (unsigned short*)(ws + 50331648 + 33554432); // 384*256 bf16
  unsigned short* W1t = (unsigned short*)(ws + 50331648 + 33554432 + 196608);
  float* stats = (float*)(ws + 50331648 + 33554432 + 196608 + 131072); // 1024 f32
  unsigned short* Y2 = X;  // X buffer free after gemm1

  nn_interp<<<2688, 256, 0, stream>>>(xyz1, xyz2, points2, points1,
                                      W0, W1, W0t, W1t, stats, X);
  gemm_nt<CIN, false><<<1024, 256, 0, stream>>>(X, W0t, Y1, stats, nullptr, nullptr, nullptr);
  gemm_nt<CO, true><<<1024, 256, 0, stream>>>(Y1, W1t, Y2, stats + 512, stats, g0, be0);
  apply_f32<<<(size_t)ROWS * CO / (256 * 8), 256, 0, stream>>>(Y2, stats + 512, g1, be1, out);
}

// Round 16
// 127.975 us; speedup vs baseline: 1.0111x; 1.0111x over previous
//
#include <hip/hip_runtime.h>
#include <hip/hip_bf16.h>
#include <stdint.h>

#define BB 16
#define NN 4096
#define MM 1024
#define C1 128
#define C2 256
#define CIN 384
#define CO 256
#define ROWS (BB * NN)

typedef __attribute__((ext_vector_type(8))) short bf16x8;
typedef __attribute__((ext_vector_type(4))) float f32x4;

__device__ inline float u2f(uint32_t u) { union { uint32_t u; float f; } v; v.u = u; return v.f; }
__device__ inline uint32_t f2u(float f) { union { float f; uint32_t u; } v; v.f = f; return v.u; }
// round-to-nearest-even f32 -> bf16 (scalar; use pk2bf for pairs)
__device__ inline unsigned short f2bf(float f) {
  uint32_t u = f2u(f);
  uint32_t r = u + 0x7fffu + ((u >> 16) & 1u);
  return (unsigned short)(r >> 16);
}
__device__ inline float bflo(uint32_t w) { return u2f(w << 16); }
__device__ inline float bfhi(uint32_t w) { return u2f(w & 0xffff0000u); }
// packed RNE f32x2 -> bf16x2 (v_cvt_pk_bf16_f32; bit-identical to f2bf pair)
__device__ inline uint32_t pk2bf(float lo, float hi) {
  union { __hip_bfloat162 h; uint32_t u; } c;
  c.h = __float22bfloat162_rn(make_float2(lo, hi));
  return c.u;
}

// ------------------- three_nn + interp + concat + weight prep (one launch)
// NN blocks are bids 0..2047 (dispatch FIRST -> full occupancy from start);
// weight-prep strips are bids 2048..2687 (tail backfill).
// Sorted top-3 insert via v_med3_f32 (bit-exact selection, no rounding):
// with e0<=e1<=e2: e2'=med3(e1,e2,d), e1'=med3(e0,e1,d), e0'=min(e0,d).
// VALU-ISSUE-bound (r13 dual-acc and r15 SoA both refuted alternatives);
// distance formula locked to reference rounding (selection flips cost O(0.3)).
#define NN_INS(dd, jj_)                                            \
  {                                                                \
    bool c0 = (dd) < e0, c1 = (dd) < e1, c2 = (dd) < e2;           \
    e2 = __builtin_amdgcn_fmed3f(e1, e2, (dd));                    \
    e1 = __builtin_amdgcn_fmed3f(e0, e1, (dd));                    \
    e0 = fminf(e0, (dd));                                          \
    i2 = c2 ? (c1 ? i1 : (jj_)) : i2;                              \
    i1 = c1 ? (c0 ? i0 : (jj_)) : i1;                              \
    i0 = c0 ? (jj_) : i0;                                          \
  }

__global__ __launch_bounds__(256) void nn_interp(const float* __restrict__ xyz1,
                                                 const float* __restrict__ xyz2,
                                                 const float* __restrict__ points2,
                                                 const float* __restrict__ points1,
                                                 const float* __restrict__ W0,
                                                 const float* __restrict__ W1,
                                                 unsigned short* __restrict__ W0t,
                                                 unsigned short* __restrict__ W1t,
                                                 float* __restrict__ stats,
                                                 unsigned short* __restrict__ X) {
  int t = threadIdx.x, bid = blockIdx.x;
  if (bid >= 2048) {  // ---- weight prep strips (tail) ----
    int wb = bid - 2048;
    if (wb == 0) { stats[t] = 0.f; stats[256 + t] = 0.f; }
    if (wb == 1) { stats[512 + t] = 0.f; stats[768 + t] = 0.f; }
    if (wb < 384) {
      int i = wb * 256 + t;           // W0t[n][k], k over 384
      int n = i / CIN, k = i - n * CIN;
      W0t[i] = f2bf(W0[(size_t)k * CO + n]);
    } else {
      int n = wb - 384;               // W1t[n][k], k = t
      W1t[n * CO + t] = f2bf(W1[(size_t)t * CO + n]);
    }
    return;
  }
  __shared__ float4 q[MM];   // 16 KB
  __shared__ int sid[96];
  __shared__ float swt[96];
  int b = bid >> 7;                 // 128 blocks per batch
  int qbase = (bid & 127) << 5;     // 32 queries per block
  const float* x2 = xyz2 + (size_t)b * MM * 3;
  for (int j = t; j < MM; j += 256)
    q[j] = make_float4(x2[j * 3 + 0], x2[j * 3 + 1], x2[j * 3 + 2], 0.f);
  __syncthreads();
  int n = qbase + (t >> 3);
  int tq = t & 7;
  const float* p = xyz1 + ((size_t)b * NN + n) * 3;
  float px = p[0], py = p[1], pz = p[2];
  float e0 = 1e30f, e1 = 1e30f, e2 = 1e30f;
  int i0 = 0, i1 = 0, i2 = 0;
#pragma unroll 8
  for (int jj = 0; jj < MM / 8; ++jj) {
    int j = jj * 8 + tq;
    float4 qv = q[j];
    float dx = px - qv.x, dy = py - qv.y, dz = pz - qv.z;
    float d = dx * dx + dy * dy + dz * dz;
    NN_INS(d, j);
  }
#pragma unroll
  for (int mk = 1; mk <= 4; mk <<= 1) {
    float f0 = __shfl_xor(e0, mk), f1 = __shfl_xor(e1, mk), f2 = __shfl_xor(e2, mk);
    int j0 = __shfl_xor(i0, mk), j1 = __shfl_xor(i1, mk), j2 = __shfl_xor(i2, mk);
    NN_INS(f0, j0);
    NN_INS(f1, j1);
    NN_INS(f2, j2);
  }
  if (tq == 0) {
    float a0 = fmaxf(e0, 1e-10f), a1 = fmaxf(e1, 1e-10f), a2 = fmaxf(e2, 1e-10f);
    float v0 = 1.f / a0, v1 = 1.f / a1, v2 = 1.f / a2;
    float inv = 1.f / (v0 + v1 + v2);
    int qi = t >> 3;
    sid[qi * 3 + 0] = i0; sid[qi * 3 + 1] = i1; sid[qi * 3 + 2] = i2;
    swt[qi * 3 + 0] = v0 * inv; swt[qi * 3 + 1] = v1 * inv; swt[qi * 3 + 2] = v2 * inv;
  }
  __syncthreads();
  // ---- interp + concat: thread t owns row r = t>>3, chunk lane s = t&7.
  // Chunks s+8i: i=0..3 -> points2 (interp), i=4,5 -> points1 (copy).
  {
    int r = t >> 3, s = t & 7;
    size_t grow = (size_t)b * NN + qbase + r;
    unsigned short* xr = X + grow * CIN;
    const float* p2 = points2 + (size_t)b * MM * C2;
    float w0 = swt[r * 3], w1 = swt[r * 3 + 1], w2 = swt[r * 3 + 2];
    const float* a0 = p2 + (size_t)sid[r * 3 + 0] * C2;
    const float* a1 = p2 + (size_t)sid[r * 3 + 1] * C2;
    const float* a2 = p2 + (size_t)sid[r * 3 + 2] * C2;
#pragma unroll
    for (int i = 0; i < 4; ++i) {
      int c0 = (s + 8 * i) * 8;
      float4 x0 = *(const float4*)(a0 + c0), x1 = *(const float4*)(a0 + c0 + 4);
      float4 y0 = *(const float4*)(a1 + c0), y1 = *(const float4*)(a1 + c0 + 4);
      float4 z0 = *(const float4*)(a2 + c0), z1 = *(const float4*)(a2 + c0 + 4);
      uint4 o4;
      o4.x = pk2bf(w0 * x0.x + w1 * y0.x + w2 * z0.x, w0 * x0.y + w1 * y0.y + w2 * z0.y);
      o4.y = pk2bf(w0 * x0.z + w1 * y0.z + w2 * z0.z, w0 * x0.w + w1 * y0.w + w2 * z0.w);
      o4.z = pk2bf(w0 * x1.x + w1 * y1.x + w2 * z1.x, w0 * x1.y + w1 * y1.y + w2 * z1.y);
      o4.w = pk2bf(w0 * x1.z + w1 * y1.z + w2 * z1.z, w0 * x1.w + w1 * y1.w + w2 * z1.w);
      *(uint4*)(xr + c0) = o4;
    }
    const float* ap = points1 + grow * C1;
#pragma unroll
    for (int i = 0; i < 2; ++i) {
      int c0 = (s + 8 * i) * 8;
      float4 x0 = *(const float4*)(ap + c0), x1 = *(const float4*)(ap + c0 + 4);
      uint4 o4;
      o4.x = pk2bf(x0.x, x0.y); o4.y = pk2bf(x0.z, x0.w);
      o4.z = pk2bf(x1.x, x1.y); o4.w = pk2bf(x1.z, x1.w);
      *(uint4*)(xr + C2 + c0) = o4;
    }
  }
}

// ---------------------------------------------------------------- bf16 GEMM
// C[m][n] = sum_k A'[m][k] * Bt[n][k];  A' = FUSE ? relu(A*sc+sh) : A.
// (round-11 proven form) Ping-pong A regs + counted vmcnt before raw
// s_barrier: vmcnt(4) waits only the 4 older B gload_lds; A-register loads
// stay in flight across the barrier. Prefetch slots contain RAW loads only
// (value-dependent conversions there force an early vmcnt wait -- r12 failure).
__device__ inline void gload_lds16(const void* g, void* l) {
  __builtin_amdgcn_global_load_lds(
      (const __attribute__((address_space(1))) void*)g,
      (__attribute__((address_space(3))) void*)l, 16, 0, 0);
}

template <int K, bool FUSE>
__global__ __launch_bounds__(256, 3) void gemm_nt(const unsigned short* __restrict__ A,
                                                  const unsigned short* __restrict__ Bt,
                                                  unsigned short* __restrict__ C,
                                                  float* __restrict__ stats,
                                                  const float* __restrict__ statsPrev,
                                                  const float* __restrict__ g,
                                                  const float* __restrict__ be) {
  constexpr int NT = K / 64;
  __shared__ unsigned short lB[2][128 * 64];  // [buf][n][k] swizzled chunks
  __shared__ float sdat[256];
  __shared__ float lscsh[FUSE ? 512 : 4];
  int t = threadIdx.x;
  int lane = t & 63, w = t >> 6;
  // pair-XCD swizzle: the two 128-col panels of one row-tile get bids 8 apart
  int gb = blockIdx.x >> 4, rb = blockIdx.x & 15;
  int pq = rb >> 3, ti = (gb << 3) + (rb & 7);
  int m0 = ti * 128, n0 = pq * 128;
  int lrow = lane >> 3;                       // 0..7
  int lcol = (((lane & 7) ^ lrow) << 3);      // T2 source-side swizzled chunk

#define STAGE_B(buf, tt_)                                                      \
  {                                                                            \
    _Pragma("unroll") for (int i = 0; i < 4; ++i) {                            \
      int row = i * 32 + w * 8 + lrow;                                         \
      gload_lds16(Bt + (size_t)(n0 + row) * K + (tt_) * 64 + lcol,             \
                  &lB[buf][i * 2048 + w * 512]);                               \
    }                                                                          \
    asm volatile("" ::: "memory");  /* pin issue order: gloads before A */     \
  }

  const unsigned short* Ab = A + (size_t)(m0 + w * 32 + (lane & 15)) * K + (lane >> 4) * 8;
#define LOAD_A(dst, tt_)                                                       \
  {                                                                            \
    dst[0] = *(const uint4*)(Ab + (tt_) * 64);                                 \
    dst[1] = *(const uint4*)(Ab + (size_t)16 * K + (tt_) * 64);                \
    dst[2] = *(const uint4*)(Ab + (tt_) * 64 + 32);                            \
    dst[3] = *(const uint4*)(Ab + (size_t)16 * K + (tt_) * 64 + 32);           \
  }

  uint4 afA[4], afB[4];
  STAGE_B(0, 0);
  LOAD_A(afA, 0);
  sdat[t] = 0.f;
  if (FUSE) {
    float mean = statsPrev[t] * (1.f / ROWS);
    float var = statsPrev[256 + t] * (1.f / ROWS) - mean * mean;
    float sc = g[t] * rsqrtf(var + 1e-3f);
    lscsh[t] = sc;
    lscsh[256 + t] = be[t] - mean * sc;
  }
  __syncthreads();  // prologue: full drain, B(0) visible

  f32x4 acc[2][8] = {};

#define COMPUTE(buf, tt_, AF)                                                  \
  {                                                                            \
    _Pragma("unroll") for (int kk = 0; kk < 2; ++kk) {                         \
      int ko = kk * 32 + (lane >> 4) * 8;                                      \
      bf16x8 bfr[8];                                                           \
      _Pragma("unroll") for (int n2 = 0; n2 < 8; ++n2) {                       \
        int row = n2 * 16 + (lane & 15);                                       \
        bfr[n2] = *(const bf16x8*)&lB[buf][row * 64 + (ko ^ ((row & 7) << 3))];\
      }                                                                        \
      bf16x8 af[2];                                                            \
      _Pragma("unroll") for (int m = 0; m < 2; ++m) {                          \
        union { uint4 u; bf16x8 h; uint32_t wv[4]; } cv;                       \
        cv.u = AF[kk * 2 + m];                                                 \
        if (FUSE) {                                                            \
          int cb = (tt_) * 64 + ko;                                            \
          float4 sa = *(const float4*)&lscsh[cb];                              \
          float4 sb = *(const float4*)&lscsh[cb + 4];                          \
          float4 ha = *(const float4*)&lscsh[256 + cb];                        \
          float4 hb = *(const float4*)&lscsh[256 + cb + 4];                    \
          float scf[8] = {sa.x, sa.y, sa.z, sa.w, sb.x, sb.y, sb.z, sb.w};     \
          float shf[8] = {ha.x, ha.y, ha.z, ha.w, hb.x, hb.y, hb.z, hb.w};     \
          _Pragma("unroll") for (int q_ = 0; q_ < 4; ++q_) {                   \
            float lo = fmaxf(bflo(cv.wv[q_]) * scf[2 * q_] + shf[2 * q_], 0.f);\
            float hi = fmaxf(bfhi(cv.wv[q_]) * scf[2 * q_ + 1] + shf[2 * q_ + 1], 0.f); \
            cv.wv[q_] = pk2bf(lo, hi);                                         \
          }                                                                    \
        }                                                                      \
        af[m] = cv.h;                                                          \
      }                                                                        \
      _Pragma("unroll") for (int m = 0; m < 2; ++m)                            \
        _Pragma("unroll") for (int n2 = 0; n2 < 8; ++n2)                       \
          acc[m][n2] = __builtin_amdgcn_mfma_f32_16x16x32_bf16(af[m], bfr[n2], acc[m][n2], 0, 0, 0); \
    }                                                                          \
  }

#define CBAR()                                                                 \
  {                                                                            \
    asm volatile("s_waitcnt vmcnt(4)" ::: "memory");                           \
    __builtin_amdgcn_s_barrier();                                              \
  }

#pragma unroll
  for (int tt = 0; tt < NT; tt += 2) {
    STAGE_B(1, tt + 1);
    LOAD_A(afB, tt + 1);
    COMPUTE(0, tt, afA);
    CBAR();
    if (tt + 2 < NT) {
      STAGE_B(0, tt + 2);
      LOAD_A(afA, tt + 2);
    }
    COMPUTE(1, tt + 1, afB);
    if (tt + 2 < NT) CBAR();
  }
#undef STAGE_B
#undef LOAD_A
#undef COMPUTE
#undef CBAR

  // ---- C write (bf16, raw pre-BN values) ----
  int crow0 = m0 + w * 32 + (lane >> 4) * 4;
  int ccol0 = n0 + (lane & 15);
#pragma unroll
  for (int m = 0; m < 2; ++m)
#pragma unroll
    for (int n2 = 0; n2 < 8; ++n2) {
      size_t rb2 = (size_t)(crow0 + m * 16);
      int cc = ccol0 + n2 * 16;
#pragma unroll
      for (int j = 0; j < 4; ++j)
        C[(rb2 + j) * CO + cc] = f2bf(acc[m][n2][j]);
    }
  // ---- fused BN stats ----
#pragma unroll
  for (int n2 = 0; n2 < 8; ++n2) {
    float s = 0.f, qq = 0.f;
#pragma unroll
    for (int m = 0; m < 2; ++m)
#pragma unroll
      for (int j = 0; j < 4; ++j) { float v = acc[m][n2][j]; s += v; qq += v * v; }
    s += __shfl_xor(s, 16); qq += __shfl_xor(qq, 16);
    s += __shfl_xor(s, 32); qq += __shfl_xor(qq, 32);
    if (lane < 16) {
      int cl = n2 * 16 + lane;
      atomicAdd(&sdat[cl], s);
      atomicAdd(&sdat[128 + cl], qq);
    }
  }
  __syncthreads();
  if (t < 128) {
    atomicAdd(&stats[n0 + t], sdat[t]);
    atomicAdd(&stats[256 + n0 + t], sdat[128 + t]);
  }
}

// ------------------- BN+ReLU apply, fp32 out (finalize folded into prologue)
__global__ __launch_bounds__(256) void apply_f32(const unsigned short* __restrict__ Y,
                                                 const float* __restrict__ stats2,
                                                 const float* __restrict__ g,
                                                 const float* __restrict__ be,
                                                 float* __restrict__ out) {
  __shared__ float sc[256], sh[256];
  int t = threadIdx.x;
  {
    float mean = stats2[t] * (1.f / ROWS);
    float var = stats2[256 + t] * (1.f / ROWS) - mean * mean;
    float s = g[t] * rsqrtf(var + 1e-3f);
    sc[t] = s;
    sh[t] = be[t] - mean * s;
  }
  __syncthreads();
  size_t base = ((size_t)blockIdx.x * 256 + t) * 8;
  int c0 = (int)(base & 255);
  uint4 v = *(const uint4*)(Y + base);
  uint32_t wv[4] = {v.x, v.y, v.z, v.w};
  float o[8];
#pragma unroll
  for (int q = 0; q < 4; ++q) {
    o[2 * q]     = fmaxf(bflo(wv[q]) * sc[c0 + 2 * q] + sh[c0 + 2 * q], 0.f);
    o[2 * q + 1] = fmaxf(bfhi(wv[q]) * sc[c0 + 2 * q + 1] + sh[c0 + 2 * q + 1], 0.f);
  }
  *(float4*)(out + base) = make_float4(o[0], o[1], o[2], o[3]);
  *(float4*)(out + base + 4) = make_float4(o[4], o[5], o[6], o[7]);
}

extern "C" void kernel_launch(void* const* d_in, const int* in_sizes, int n_in,
                              void* d_out, int out_size, void* d_ws, size_t ws_size,
                              hipStream_t stream) {
  const float* xyz1    = (const float*)d_in[0];
  const float* xyz2    = (const float*)d_in[1];
  const float* points1 = (const float*)d_in[2];
  const float* points2 = (const float*)d_in[3];
  const float* W0      = (const float*)d_in[4];
  const float* g0      = (const float*)d_in[6];
  const float* be0     = (const float*)d_in[7];
  const float* W1      = (const float*)d_in[8];
  const float* g1      = (const float*)d_in[10];
  const float* be1     = (const float*)d_in[11];
  float* out = (float*)d_out;

  // workspace layout (bytes)
  char* ws = (char*)d_ws;
  unsigned short* X   = (unsigned short*)(ws);                       // ROWS*384 bf16 (reused for Y2)
  unsigned short* Y1  = (unsigned short*)(ws + 50331648);            // ROWS*256 bf16
  unsigned short* W0t = (unsigned short*)(ws + 50331648 + 33554432); // 384*256 bf16
  unsigned short* W1t = (unsigned short*)(ws + 50331648 + 33554432 + 196608);
  float* stats = (float*)(ws + 50331648 + 33554432 + 196608 + 131072); // 1024 f32
  unsigned short* Y2 = X;  // X buffer free after gemm1

  nn_interp<<<2688, 256, 0, stream>>>(xyz1, xyz2, points2, points1,
                                      W0, W1, W0t, W1t, stats, X);
  gemm_nt<CIN, false><<<1024, 256, 0, stream>>>(X, W0t, Y1, stats, nullptr, nullptr, nullptr);
  gemm_nt<CO, true><<<1024, 256, 0, stream>>>(Y1, W1t, Y2, stats + 512, stats, g0, be0);
  apply_f32<<<(size_t)ROWS * CO / (256 * 8), 256, 0, stream>>>(Y2, stats + 512, g1, be1, out);
}